// Round 2
// baseline (717.596 us; speedup 1.0000x reference)
//
#include <hip/hip_runtime.h>
#include <hip/hip_bf16.h>

typedef __bf16 bf16;
typedef __bf16 bf16x4 __attribute__((ext_vector_type(4)));
typedef __bf16 bf16x8 __attribute__((ext_vector_type(8)));
typedef float floatx4 __attribute__((ext_vector_type(4)));
typedef float float4v __attribute__((ext_vector_type(4)));

#define MFMA16(a, b, c) __builtin_amdgcn_mfma_f32_16x16x32_bf16(a, b, c, 0, 0, 0)

constexpr int B_ = 2, S_ = 2048, DIM_ = 1024, H_ = 16, HD_ = 64;
constexpr float SCALE_ = 0.125f;   // HD^-0.5
constexpr float EPS_ = 1e-8f;

// ---------------------------------------------------------------- helpers
__device__ __forceinline__ void gload_lds16(const bf16* g, bf16* l) {
    __builtin_amdgcn_global_load_lds(
        (const __attribute__((address_space(1))) void*)g,
        (__attribute__((address_space(3))) void*)l, 16, 0, 0);
}

// ---------------------------------------------------------------- f32 -> bf16
__global__ __launch_bounds__(256) void cvt_kernel(const float* __restrict__ in,
                                                  bf16* __restrict__ out, int n4) {
    int i = blockIdx.x * 256 + threadIdx.x;
    if (i >= n4) return;
    float4v v = ((const float4v*)in)[i];
    bf16x4 o;
    o[0] = (bf16)v[0]; o[1] = (bf16)v[1]; o[2] = (bf16)v[2]; o[3] = (bf16)v[3];
    ((bf16x4*)out)[i] = o;
}

// ---------------------------------------------------------------- GEMM C = A(MxK) * B(NxK)^T
template<int OUTF32, int BIASED>
__global__ __launch_bounds__(256) void gemm_bt(const bf16* __restrict__ A,
                                               const bf16* __restrict__ B,
                                               void* __restrict__ Cp,
                                               const float* __restrict__ bias,
                                               int M, int N, int K) {
    __shared__ bf16 As[128 * 64];
    __shared__ bf16 Bs[128 * 64];
    const int lane = threadIdx.x & 63, wid = threadIdx.x >> 6;
    const int colL = lane & 15, grp = lane >> 4;
    const int bm = blockIdx.y * 128, bn = blockIdx.x * 128;
    const int wr = wid >> 1, wc = wid & 1;

    floatx4 acc[4][4];
#pragma unroll
    for (int m = 0; m < 4; ++m)
#pragma unroll
        for (int n = 0; n < 4; ++n) acc[m][n] = (floatx4){0.f, 0.f, 0.f, 0.f};

    for (int k0 = 0; k0 < K; k0 += 64) {
#pragma unroll
        for (int i = 0; i < 4; ++i) {
            int c = wid * 256 + i * 64 + lane;
            int row = c >> 3, sub = c & 7;
            gload_lds16(A + (size_t)(bm + row) * K + k0 + sub * 8,
                        &As[(wid * 256 + i * 64) * 8]);
            gload_lds16(B + (size_t)(bn + row) * K + k0 + sub * 8,
                        &Bs[(wid * 256 + i * 64) * 8]);
        }
        __syncthreads();
#pragma unroll
        for (int ks = 0; ks < 2; ++ks) {
            bf16x8 af[4], bfr[4];
#pragma unroll
            for (int m = 0; m < 4; ++m)
                af[m] = *(const bf16x8*)(&As[(wr * 64 + m * 16 + colL) * 64 + ks * 32 + grp * 8]);
#pragma unroll
            for (int n = 0; n < 4; ++n)
                bfr[n] = *(const bf16x8*)(&Bs[(wc * 64 + n * 16 + colL) * 64 + ks * 32 + grp * 8]);
#pragma unroll
            for (int m = 0; m < 4; ++m)
#pragma unroll
                for (int n = 0; n < 4; ++n)
                    acc[m][n] = MFMA16(af[m], bfr[n], acc[m][n]);
        }
        __syncthreads();
    }

#pragma unroll
    for (int m = 0; m < 4; ++m)
#pragma unroll
        for (int n = 0; n < 4; ++n)
#pragma unroll
            for (int r = 0; r < 4; ++r) {
                int row = bm + wr * 64 + m * 16 + grp * 4 + r;
                int col = bn + wc * 64 + n * 16 + colL;
                float v = acc[m][n][r];
                if (BIASED) v += bias[col];
                if (OUTF32) ((float*)Cp)[(size_t)row * N + col] = v;
                else        ((bf16*)Cp)[(size_t)row * N + col] = (bf16)v;
            }
}

// ---------------------------------------------------------------- RoPE (+scale), (B,S,DIM-slice) -> (B,H,S,HD)
__global__ __launch_bounds__(256) void rope_kernel(const bf16* __restrict__ in,
                                                   const float* __restrict__ fr,
                                                   bf16* __restrict__ out,
                                                   int in_ld, float scale) {
    int tid = blockIdx.x * 256 + threadIdx.x;
    int j = tid & 7, h = (tid >> 3) & 15, s = (tid >> 7) & 2047, b = tid >> 18;
    bf16x8 x = *(const bf16x8*)(in + (size_t)(b * 2048 + s) * in_ld + h * 64 + j * 8);
    const float* f = fr + (size_t)(b * 2048 + s) * 64 + j * 4;
    bf16x8 o;
#pragma unroll
    for (int i = 0; i < 4; ++i) {
        float c = f[i], sn = f[32 + i];
        float x0 = (float)x[2 * i], x1 = (float)x[2 * i + 1];
        o[2 * i]     = (bf16)((x0 * c - x1 * sn) * scale);
        o[2 * i + 1] = (bf16)((x0 * sn + x1 * c) * scale);
    }
    *(bf16x8*)(out + ((size_t)(b * 16 + h) * 2048 + s) * 64 + j * 8) = o;
}

// ---------------------------------------------------------------- V transpose: KVp(B,S,2048) v-part -> Vt(B,H,HD,S)
__global__ __launch_bounds__(256) void vtrans_kernel(const bf16* __restrict__ KVp,
                                                     bf16* __restrict__ Vt) {
    int bid = blockIdx.x;
    int sb = bid & 31, h = (bid >> 5) & 15, b = bid >> 9;
    __shared__ bf16 tile[64][66];
    int tid = threadIdx.x;
#pragma unroll
    for (int i = 0; i < 2; ++i) {
        int c = tid + i * 256;
        int row = c >> 3, sub = c & 7;
        bf16x8 x = *(const bf16x8*)(KVp + (size_t)(b * 2048 + sb * 64 + row) * 2048
                                    + 1024 + h * 64 + sub * 8);
#pragma unroll
        for (int k = 0; k < 8; ++k) tile[row][sub * 8 + k] = x[k];
    }
    __syncthreads();
#pragma unroll
    for (int i = 0; i < 2; ++i) {
        int c = tid + i * 256;
        int drow = c >> 3, sub = c & 7;
        bf16x8 o;
#pragma unroll
        for (int k = 0; k < 8; ++k) o[k] = tile[sub * 8 + k][drow];
        *(bf16x8*)(Vt + ((size_t)(b * 16 + h) * 64 + drow) * 2048 + sb * 64 + sub * 8) = o;
    }
}

// ---------------------------------------------------------------- fused attention (swapped-operand flash)
// Block: (b, h, 16 q-rows). 4 waves split k 4-ways (512 each).
// s-frags via mfma(K,Q): lane owns q = lane&15, k = grp*4+r. PV via mfma(Vt,P): o_acc
// also per-lane-q. Combine (m,U,o) across waves in LDS, then pass-2 streams attn out.
__global__ __launch_bounds__(256) void attn_kernel(const bf16* __restrict__ Qr,
                                                   const bf16* __restrict__ Kr,
                                                   const bf16* __restrict__ Vt,
                                                   const float* __restrict__ mask,
                                                   const float* __restrict__ prior,
                                                   float* __restrict__ attn_out,
                                                   bf16* __restrict__ O) {
    struct Comb { float m[4][16]; float U[4][16]; float o[4][16][68]; };
    __shared__ union SM { bf16 p[4][1024]; Comb c; } sm;
    __shared__ float lds_gm[16], lds_iu[16];

    const int lane = threadIdx.x & 63, wv = threadIdx.x >> 6;
    const int colL = lane & 15, grp = lane >> 4;
    const int bidx = blockIdx.x;                  // b*2048 + h*128 + qt
    const int qt = bidx & 127, h = (bidx >> 7) & 15, b = bidx >> 11;
    const int bh = b * H_ + h;
    const int q0 = qt * 16;

    const bf16* Qbase = Qr + ((size_t)bh * S_ + q0) * HD_;
    const bf16* Kbase = Kr + (size_t)bh * S_ * HD_;
    const bf16* Vbase = Vt + (size_t)bh * HD_ * S_;
    const float* Mrow = mask + ((size_t)b * S_ + q0 + colL) * S_;
    const float* Prow = prior + ((size_t)b * S_ + q0 + colL) * S_;

    // Q fragments (B-operand): lane holds Q[q=colL][grp*8..+8] (+32 for d-half 1)
    bf16x8 qf0 = *(const bf16x8*)(Qbase + (size_t)colL * HD_ + grp * 8);
    bf16x8 qf1 = *(const bf16x8*)(Qbase + (size_t)colL * HD_ + 32 + grp * 8);

    const int kbase = wv * 512;
    bf16* P = sm.p[wv];
    const int swz = (colL & 7) << 3;              // XOR swizzle (elem units) for P bounce

    float m_run = -1e30f, U = 0.f;
    floatx4 oT[4];
#pragma unroll
    for (int dt = 0; dt < 4; ++dt) oT[dt] = (floatx4){0.f, 0.f, 0.f, 0.f};

    // ---------------- pass 1: online m, U, O^T accumulate
    for (int kt = 0; kt < 8; ++kt) {
        const int k0 = kbase + kt * 64;
        floatx4 s[4];
#pragma unroll
        for (int ct = 0; ct < 4; ++ct) {
            const bf16* kb = Kbase + (size_t)(k0 + ct * 16 + colL) * HD_ + grp * 8;
            floatx4 acc = (floatx4){0.f, 0.f, 0.f, 0.f};
            acc = MFMA16(*(const bf16x8*)kb, qf0, acc);
            acc = MFMA16(*(const bf16x8*)(kb + 32), qf1, acc);
            s[ct] = acc;
        }
        float mt = -1e30f;
#pragma unroll
        for (int ct = 0; ct < 4; ++ct) {
            float4v mk = *(const float4v*)(Mrow + k0 + ct * 16 + grp * 4);
#pragma unroll
            for (int r = 0; r < 4; ++r) {
                s[ct][r] += mk[r];
                mt = fmaxf(mt, s[ct][r]);
            }
        }
        mt = fmaxf(mt, __shfl_xor(mt, 16, 64));
        mt = fmaxf(mt, __shfl_xor(mt, 32, 64));
        const float mn = fmaxf(m_run, mt);
        const float alpha = __expf(m_run - mn);
        m_run = mn;
        float ua = 0.f;
#pragma unroll
        for (int ct = 0; ct < 4; ++ct) {
            float4v pr = *(const float4v*)(Prow + k0 + ct * 16 + grp * 4);
            bf16x4 pw;
#pragma unroll
            for (int r = 0; r < 4; ++r) {
                float tv = __expf(s[ct][r] - mn) * fmaxf(pr[r], EPS_);
                ua += tv;
                pw[r] = (bf16)tv;
            }
            *(bf16x4*)&P[(colL * 64 + ct * 16 + grp * 4) ^ swz] = pw;
        }
        ua += __shfl_xor(ua, 16, 64);
        ua += __shfl_xor(ua, 32, 64);
        U = U * alpha + ua;
#pragma unroll
        for (int dt = 0; dt < 4; ++dt) oT[dt] *= alpha;
#pragma unroll
        for (int ks = 0; ks < 2; ++ks) {
            bf16x8 pb = *(const bf16x8*)&P[(colL * 64 + ks * 32 + grp * 8) ^ swz];
#pragma unroll
            for (int dt = 0; dt < 4; ++dt) {
                const bf16* vb = Vbase + (size_t)(dt * 16 + colL) * S_ + k0 + ks * 32 + grp * 8;
                oT[dt] = MFMA16(*(const bf16x8*)vb, pb, oT[dt]);
            }
        }
    }

    // ---------------- cross-wave combine
    __syncthreads();                 // all waves done with P regions
    sm.c.m[wv][colL] = m_run;        // all grps write same value (benign)
    sm.c.U[wv][colL] = U;
#pragma unroll
    for (int dt = 0; dt < 4; ++dt)
        *(float4v*)&sm.c.o[wv][colL][dt * 16 + grp * 4] = oT[dt];
    __syncthreads();

    {
        const int t = threadIdx.x;
        const int q = t >> 4, c4 = (t & 15) * 4;
        float mw[4], sw4[4];
#pragma unroll
        for (int w = 0; w < 4; ++w) mw[w] = sm.c.m[w][q];
        float gm = fmaxf(fmaxf(mw[0], mw[1]), fmaxf(mw[2], mw[3]));
        float Us = 0.f;
#pragma unroll
        for (int w = 0; w < 4; ++w) {
            sw4[w] = __expf(mw[w] - gm);
            Us += sm.c.U[w][q] * sw4[w];
        }
        const float iu = 1.0f / Us;
        float4v o4 = (float4v){0.f, 0.f, 0.f, 0.f};
#pragma unroll
        for (int w = 0; w < 4; ++w) {
            float4v ov = *(const float4v*)&sm.c.o[w][q][c4];
#pragma unroll
            for (int j = 0; j < 4; ++j) o4[j] += ov[j] * sw4[w];
        }
        bf16x4 ow;
#pragma unroll
        for (int j = 0; j < 4; ++j) ow[j] = (bf16)(o4[j] * iu);
        *(bf16x4*)(O + ((size_t)b * S_ + q0 + q) * DIM_ + h * HD_ + c4) = ow;
        if ((t & 15) == 0) { lds_gm[q] = gm; lds_iu[q] = iu; }
    }
    __syncthreads();

    // ---------------- pass 2: recompute logits, stream attn = e*p/U (float4)
    const float m_l = lds_gm[colL];
    const float iuL = lds_iu[colL];
    float* Abase = attn_out + ((size_t)bh * S_ + q0 + colL) * S_;
    for (int kt = 0; kt < 8; ++kt) {
        const int k0 = kbase + kt * 64;
#pragma unroll
        for (int ct = 0; ct < 4; ++ct) {
            const bf16* kb = Kbase + (size_t)(k0 + ct * 16 + colL) * HD_ + grp * 8;
            floatx4 acc = (floatx4){0.f, 0.f, 0.f, 0.f};
            acc = MFMA16(*(const bf16x8*)kb, qf0, acc);
            acc = MFMA16(*(const bf16x8*)(kb + 32), qf1, acc);
            float4v mk = *(const float4v*)(Mrow + k0 + ct * 16 + grp * 4);
            float4v pr = *(const float4v*)(Prow + k0 + ct * 16 + grp * 4);
            float4v o;
#pragma unroll
            for (int r = 0; r < 4; ++r)
                o[r] = __expf(acc[r] + mk[r] - m_l) * fmaxf(pr[r], EPS_) * iuL;
            *(float4v*)(Abase + k0 + ct * 16 + grp * 4) = o;
        }
    }
}

// ---------------------------------------------------------------- launch
extern "C" void kernel_launch(void* const* d_in, const int* in_sizes, int n_in,
                              void* d_out, int out_size, void* d_ws, size_t ws_size,
                              hipStream_t stream) {
    const float* q_x   = (const float*)d_in[0];
    const float* kv_x  = (const float*)d_in[1];
    const float* q_fr  = (const float*)d_in[2];
    const float* k_fr  = (const float*)d_in[3];
    const float* maskp = (const float*)d_in[4];
    const float* prior = (const float*)d_in[5];
    const float* Wq    = (const float*)d_in[6];
    const float* Wkv   = (const float*)d_in[7];
    const float* Wproj = (const float*)d_in[8];
    const float* bproj = (const float*)d_in[9];

    float* out_x    = (float*)d_out;                       // (B,S,DIM)
    float* out_attn = out_x + (size_t)B_ * S_ * DIM_;      // (B,H,S,S)

    char* w = (char*)d_ws;
    bf16* qx_b  = (bf16*)(w + (size_t)0);          //  8 MiB
    bf16* kvx_b = (bf16*)(w + ((size_t)8  << 20)); //  8 MiB
    bf16* wq_b  = (bf16*)(w + ((size_t)16 << 20)); //  2 MiB
    bf16* wkv_b = (bf16*)(w + ((size_t)18 << 20)); //  4 MiB
    bf16* wpj_b = (bf16*)(w + ((size_t)22 << 20)); //  2 MiB
    bf16* qp    = (bf16*)(w + ((size_t)24 << 20)); //  8 MiB  (B,S,DIM)
    bf16* kvp   = (bf16*)(w + ((size_t)32 << 20)); // 16 MiB  (B,S,2*DIM)
    bf16* qr    = (bf16*)(w + ((size_t)48 << 20)); //  8 MiB  (B,H,S,HD)
    bf16* kr    = (bf16*)(w + ((size_t)56 << 20)); //  8 MiB
    bf16* vt    = (bf16*)(w + ((size_t)64 << 20)); //  8 MiB  (B,H,HD,S)
    bf16* ob    = (bf16*)(w + ((size_t)72 << 20)); //  8 MiB  (B,S,DIM)

    // f32 -> bf16 conversions
    cvt_kernel<<<4096, 256, 0, stream>>>(q_x,   qx_b,  1048576);
    cvt_kernel<<<4096, 256, 0, stream>>>(kv_x,  kvx_b, 1048576);
    cvt_kernel<<<1024, 256, 0, stream>>>(Wq,    wq_b,   262144);
    cvt_kernel<<<2048, 256, 0, stream>>>(Wkv,   wkv_b,  524288);
    cvt_kernel<<<1024, 256, 0, stream>>>(Wproj, wpj_b,  262144);

    // projections
    gemm_bt<0, 0><<<dim3(8, 32),  256, 0, stream>>>(qx_b,  wq_b,  qp,  nullptr, 4096, 1024, 1024);
    gemm_bt<0, 0><<<dim3(16, 32), 256, 0, stream>>>(kvx_b, wkv_b, kvp, nullptr, 4096, 2048, 1024);

    // RoPE + layout
    rope_kernel<<<2048, 256, 0, stream>>>(qp,  q_fr, qr, 1024, SCALE_);
    rope_kernel<<<2048, 256, 0, stream>>>(kvp, k_fr, kr, 2048, 1.0f);
    vtrans_kernel<<<1024, 256, 0, stream>>>(kvp, vt);

    // fused attention (writes attn + O)
    attn_kernel<<<4096, 256, 0, stream>>>(qr, kr, vt, maskp, prior, out_attn, ob);

    // output projection
    gemm_bt<1, 1><<<dim3(8, 32), 256, 0, stream>>>(ob, wpj_b, out_x, bproj, 4096, 1024, 1024);
}

// Round 3
// 703.661 us; speedup vs baseline: 1.0198x; 1.0198x over previous
//
#include <hip/hip_runtime.h>
#include <hip/hip_bf16.h>

typedef __bf16 bf16;
typedef __bf16 bf16x4 __attribute__((ext_vector_type(4)));
typedef __bf16 bf16x8 __attribute__((ext_vector_type(8)));
typedef float floatx4 __attribute__((ext_vector_type(4)));
typedef float float4v __attribute__((ext_vector_type(4)));

#define MFMA16(a, b, c) __builtin_amdgcn_mfma_f32_16x16x32_bf16(a, b, c, 0, 0, 0)

constexpr int B_ = 2, S_ = 2048, DIM_ = 1024, H_ = 16, HD_ = 64;
constexpr float SCALE_ = 0.125f;   // HD^-0.5
constexpr float EPS_ = 1e-8f;

// ---------------------------------------------------------------- helpers
__device__ __forceinline__ void gload_lds16(const bf16* g, bf16* l) {
    __builtin_amdgcn_global_load_lds(
        (const __attribute__((address_space(1))) void*)g,
        (__attribute__((address_space(3))) void*)l, 16, 0, 0);
}

// ---------------------------------------------------------------- f32 -> bf16
__global__ __launch_bounds__(256) void cvt_kernel(const float* __restrict__ in,
                                                  bf16* __restrict__ out, int n4) {
    int i = blockIdx.x * 256 + threadIdx.x;
    if (i >= n4) return;
    float4v v = ((const float4v*)in)[i];
    bf16x4 o;
    o[0] = (bf16)v[0]; o[1] = (bf16)v[1]; o[2] = (bf16)v[2]; o[3] = (bf16)v[3];
    ((bf16x4*)out)[i] = o;
}

// ---------------------------------------------------------------- GEMM C = A(MxK) * B(NxK)^T
template<int OUTF32, int BIASED>
__global__ __launch_bounds__(256) void gemm_bt(const bf16* __restrict__ A,
                                               const bf16* __restrict__ B,
                                               void* __restrict__ Cp,
                                               const float* __restrict__ bias,
                                               int M, int N, int K) {
    __shared__ bf16 As[128 * 64];
    __shared__ bf16 Bs[128 * 64];
    const int lane = threadIdx.x & 63, wid = threadIdx.x >> 6;
    const int colL = lane & 15, grp = lane >> 4;
    const int bm = blockIdx.y * 128, bn = blockIdx.x * 128;
    const int wr = wid >> 1, wc = wid & 1;

    floatx4 acc[4][4];
#pragma unroll
    for (int m = 0; m < 4; ++m)
#pragma unroll
        for (int n = 0; n < 4; ++n) acc[m][n] = (floatx4){0.f, 0.f, 0.f, 0.f};

    for (int k0 = 0; k0 < K; k0 += 64) {
#pragma unroll
        for (int i = 0; i < 4; ++i) {
            int c = wid * 256 + i * 64 + lane;
            int row = c >> 3, sub = c & 7;
            gload_lds16(A + (size_t)(bm + row) * K + k0 + sub * 8,
                        &As[(wid * 256 + i * 64) * 8]);
            gload_lds16(B + (size_t)(bn + row) * K + k0 + sub * 8,
                        &Bs[(wid * 256 + i * 64) * 8]);
        }
        __syncthreads();
#pragma unroll
        for (int ks = 0; ks < 2; ++ks) {
            bf16x8 af[4], bfr[4];
#pragma unroll
            for (int m = 0; m < 4; ++m)
                af[m] = *(const bf16x8*)(&As[(wr * 64 + m * 16 + colL) * 64 + ks * 32 + grp * 8]);
#pragma unroll
            for (int n = 0; n < 4; ++n)
                bfr[n] = *(const bf16x8*)(&Bs[(wc * 64 + n * 16 + colL) * 64 + ks * 32 + grp * 8]);
#pragma unroll
            for (int m = 0; m < 4; ++m)
#pragma unroll
                for (int n = 0; n < 4; ++n)
                    acc[m][n] = MFMA16(af[m], bfr[n], acc[m][n]);
        }
        __syncthreads();
    }

#pragma unroll
    for (int m = 0; m < 4; ++m)
#pragma unroll
        for (int n = 0; n < 4; ++n)
#pragma unroll
            for (int r = 0; r < 4; ++r) {
                int row = bm + wr * 64 + m * 16 + grp * 4 + r;
                int col = bn + wc * 64 + n * 16 + colL;
                float v = acc[m][n][r];
                if (BIASED) v += bias[col];
                if (OUTF32) ((float*)Cp)[(size_t)row * N + col] = v;
                else        ((bf16*)Cp)[(size_t)row * N + col] = (bf16)v;
            }
}

// ---------------------------------------------------------------- RoPE (+scale), (B,S,DIM-slice) -> (B,H,S,HD)
__global__ __launch_bounds__(256) void rope_kernel(const bf16* __restrict__ in,
                                                   const float* __restrict__ fr,
                                                   bf16* __restrict__ out,
                                                   int in_ld, float scale) {
    int tid = blockIdx.x * 256 + threadIdx.x;
    int j = tid & 7, h = (tid >> 3) & 15, s = (tid >> 7) & 2047, b = tid >> 18;
    bf16x8 x = *(const bf16x8*)(in + (size_t)(b * 2048 + s) * in_ld + h * 64 + j * 8);
    const float* f = fr + (size_t)(b * 2048 + s) * 64 + j * 4;
    bf16x8 o;
#pragma unroll
    for (int i = 0; i < 4; ++i) {
        float c = f[i], sn = f[32 + i];
        float x0 = (float)x[2 * i], x1 = (float)x[2 * i + 1];
        o[2 * i]     = (bf16)((x0 * c - x1 * sn) * scale);
        o[2 * i + 1] = (bf16)((x0 * sn + x1 * c) * scale);
    }
    *(bf16x8*)(out + ((size_t)(b * 16 + h) * 2048 + s) * 64 + j * 8) = o;
}

// ---------------------------------------------------------------- V transpose: KVp(B,S,2048) v-part -> Vt(B,H,HD,S)
__global__ __launch_bounds__(256) void vtrans_kernel(const bf16* __restrict__ KVp,
                                                     bf16* __restrict__ Vt) {
    int bid = blockIdx.x;
    int sb = bid & 31, h = (bid >> 5) & 15, b = bid >> 9;
    __shared__ bf16 tile[64][66];
    int tid = threadIdx.x;
#pragma unroll
    for (int i = 0; i < 2; ++i) {
        int c = tid + i * 256;
        int row = c >> 3, sub = c & 7;
        bf16x8 x = *(const bf16x8*)(KVp + (size_t)(b * 2048 + sb * 64 + row) * 2048
                                    + 1024 + h * 64 + sub * 8);
#pragma unroll
        for (int k = 0; k < 8; ++k) tile[row][sub * 8 + k] = x[k];
    }
    __syncthreads();
#pragma unroll
    for (int i = 0; i < 2; ++i) {
        int c = tid + i * 256;
        int drow = c >> 3, sub = c & 7;
        bf16x8 o;
#pragma unroll
        for (int k = 0; k < 8; ++k) o[k] = tile[sub * 8 + k][drow];
        *(bf16x8*)(Vt + ((size_t)(b * 16 + h) * 64 + drow) * 2048 + sb * 64 + sub * 8) = o;
    }
}

// ---------------------------------------------------------------- fused attention pass A (shift-free)
// Block = (b,h,64 q rows), 4 independent waves x 16 q rows, full k sweep.
// Swapped MFMA: lane owns q=colL. t = exp(s+mask)*clip(prior). Accumulate U and
// O_un = sum t*V; store t (bf16 tiled scratch if PF32==0, f32 into attn if PF32==1).
template<int PF32>
__global__ __launch_bounds__(256) void attn_fwd(const bf16* __restrict__ Qr,
                                                const bf16* __restrict__ Kr,
                                                const bf16* __restrict__ Vt,
                                                const float* __restrict__ mask,
                                                const float* __restrict__ prior,
                                                void* __restrict__ Pout,
                                                float* __restrict__ invU_out,
                                                bf16* __restrict__ O) {
    __shared__ bf16 plds[4][1024];
    const int lane = threadIdx.x & 63, wv = threadIdx.x >> 6;
    const int colL = lane & 15, grp = lane >> 4;
    const int bidx = blockIdx.x;              // b*512 + h*32 + qb
    const int qb = bidx & 31, h = (bidx >> 5) & 15, b = bidx >> 9;
    const int bh = b * H_ + h;
    const int q0 = qb * 64 + wv * 16;         // wave's first q row

    const bf16* Qbase = Qr + ((size_t)bh * S_ + q0) * HD_;
    const bf16* Kbase = Kr + (size_t)bh * S_ * HD_;
    const bf16* Vbase = Vt + (size_t)bh * HD_ * S_;
    const float* Mrow = mask + ((size_t)b * S_ + q0 + colL) * S_;
    const float* Prow = prior + ((size_t)b * S_ + q0 + colL) * S_;

    bf16x8 qf0 = *(const bf16x8*)(Qbase + (size_t)colL * HD_ + grp * 8);
    bf16x8 qf1 = *(const bf16x8*)(Qbase + (size_t)colL * HD_ + 32 + grp * 8);

    bf16* P = plds[wv];
    const int swz = (colL & 7) << 3;

    // P-scratch (bf16 tiled): tile = (bh, qt, kt), 1024 elems, lane-order
    bf16* Pt = (bf16*)Pout + ((size_t)bh * 128 + (q0 >> 4)) * 32 * 1024;
    // f32 direct path
    float* Arow = (float*)Pout + ((size_t)bh * S_ + q0 + colL) * S_;

    float ua = 0.f;
    floatx4 oT[4];
#pragma unroll
    for (int dt = 0; dt < 4; ++dt) oT[dt] = (floatx4){0.f, 0.f, 0.f, 0.f};

    // prefetch mask/prior tile 0
    float4v mk[4], pr[4];
#pragma unroll
    for (int ct = 0; ct < 4; ++ct) {
        mk[ct] = *(const float4v*)(Mrow + ct * 16 + grp * 4);
        pr[ct] = *(const float4v*)(Prow + ct * 16 + grp * 4);
    }

    for (int kt = 0; kt < 32; ++kt) {
        const int k0 = kt * 64;
        // QK^T (swapped): s[ct][r] = logit(q=colL, k=k0+ct*16+grp*4+r)
        floatx4 s[4];
#pragma unroll
        for (int ct = 0; ct < 4; ++ct) {
            const bf16* kb = Kbase + (size_t)(k0 + ct * 16 + colL) * HD_ + grp * 8;
            floatx4 acc = (floatx4){0.f, 0.f, 0.f, 0.f};
            acc = MFMA16(*(const bf16x8*)kb, qf0, acc);
            acc = MFMA16(*(const bf16x8*)(kb + 32), qf1, acc);
            s[ct] = acc;
        }
        float4v cmk[4], cpr[4];
#pragma unroll
        for (int ct = 0; ct < 4; ++ct) { cmk[ct] = mk[ct]; cpr[ct] = pr[ct]; }
        if (kt < 31) {
#pragma unroll
            for (int ct = 0; ct < 4; ++ct) {
                mk[ct] = *(const float4v*)(Mrow + k0 + 64 + ct * 16 + grp * 4);
                pr[ct] = *(const float4v*)(Prow + k0 + 64 + ct * 16 + grp * 4);
            }
        }
        // t = exp(s+mask)*clip(prior); store; accumulate U
#pragma unroll
        for (int ct = 0; ct < 4; ++ct) {
            float4v ev;
            bf16x4 pw;
#pragma unroll
            for (int r = 0; r < 4; ++r) {
                float e = __expf(s[ct][r] + cmk[ct][r]);
                float tv = e * fmaxf(cpr[ct][r], EPS_);
                ua += tv;
                ev[r] = tv;
                pw[r] = (bf16)tv;
            }
            if (PF32) *(float4v*)(Arow + k0 + ct * 16 + grp * 4) = ev;
            else      *(bf16x4*)(Pt + (size_t)kt * 1024 + ct * 256 + lane * 4) = pw;
            *(bf16x4*)&P[(colL * 64 + ct * 16 + grp * 4) ^ swz] = pw;
        }
        // PV (transposed): oT[dt] rows d, col q
#pragma unroll
        for (int ks = 0; ks < 2; ++ks) {
            bf16x8 pb = *(const bf16x8*)&P[(colL * 64 + ks * 32 + grp * 8) ^ swz];
#pragma unroll
            for (int dt = 0; dt < 4; ++dt) {
                const bf16* vb = Vbase + (size_t)(dt * 16 + colL) * S_ + k0 + ks * 32 + grp * 8;
                oT[dt] = MFMA16(*(const bf16x8*)vb, pb, oT[dt]);
            }
        }
    }

    // U reduce across grp (rows are per colL; 4 grp-copies hold partials)
    ua += __shfl_xor(ua, 16, 64);
    ua += __shfl_xor(ua, 32, 64);
    const float iu = 1.0f / ua;
    if (grp == 0) invU_out[(size_t)bh * S_ + q0 + colL] = iu;

#pragma unroll
    for (int dt = 0; dt < 4; ++dt) {
        bf16x4 ow;
#pragma unroll
        for (int r = 0; r < 4; ++r) ow[r] = (bf16)(oT[dt][r] * iu);
        *(bf16x4*)(O + ((size_t)b * S_ + q0 + colL) * DIM_ + h * HD_ + dt * 16 + grp * 4) = ow;
    }
}

// ---------------------------------------------------------------- pass B (scratch variant): LDS transpose + scale
__global__ __launch_bounds__(256) void attn_scale_t(const bf16* __restrict__ Pbuf,
                                                    const float* __restrict__ invU,
                                                    float* __restrict__ attn) {
    __shared__ float tile[16][264];
    const int blk = blockIdx.x;               // (bh*128 + qt)*8 + kc
    const int kc = blk & 7, qt = (blk >> 3) & 127, bh = blk >> 10;
    const int t = threadIdx.x;
    const int ct = t >> 6, laneA = t & 63;
    const int q = laneA & 15, kl = ct * 16 + ((laneA >> 4) << 2);
    const bf16* base = Pbuf + (((size_t)bh * 128 + qt) * 32 + kc * 4) * 1024;
#pragma unroll
    for (int tau = 0; tau < 4; ++tau) {
        bf16x4 v = *(const bf16x4*)(base + tau * 1024 + t * 4);
#pragma unroll
        for (int r = 0; r < 4; ++r) tile[q][tau * 64 + kl + r] = (float)v[r];
    }
    __syncthreads();
    const int wv = t >> 6, lane = t & 63;
#pragma unroll
    for (int it = 0; it < 4; ++it) {
        const int row = wv * 4 + it;
        const float iu = invU[(size_t)bh * S_ + qt * 16 + row];
        float4v o;
#pragma unroll
        for (int j = 0; j < 4; ++j) o[j] = tile[row][lane * 4 + j] * iu;
        *(float4v*)(attn + ((size_t)bh * S_ + qt * 16 + row) * S_ + kc * 256 + lane * 4) = o;
    }
}

// ---------------------------------------------------------------- pass B (in-place variant): row scale
__global__ __launch_bounds__(256) void attn_scale_ip(float* __restrict__ attn,
                                                     const float* __restrict__ invU) {
    const size_t row = blockIdx.x;
    const float iu = invU[row];
    float4v* p = (float4v*)(attn + row * S_) + threadIdx.x;
    float4v a = p[0], b = p[256];
#pragma unroll
    for (int j = 0; j < 4; ++j) { a[j] *= iu; b[j] *= iu; }
    p[0] = a; p[256] = b;
}

// ---------------------------------------------------------------- launch
extern "C" void kernel_launch(void* const* d_in, const int* in_sizes, int n_in,
                              void* d_out, int out_size, void* d_ws, size_t ws_size,
                              hipStream_t stream) {
    const float* q_x   = (const float*)d_in[0];
    const float* kv_x  = (const float*)d_in[1];
    const float* q_fr  = (const float*)d_in[2];
    const float* k_fr  = (const float*)d_in[3];
    const float* maskp = (const float*)d_in[4];
    const float* prior = (const float*)d_in[5];
    const float* Wq    = (const float*)d_in[6];
    const float* Wkv   = (const float*)d_in[7];
    const float* Wproj = (const float*)d_in[8];
    const float* bproj = (const float*)d_in[9];

    float* out_x    = (float*)d_out;                       // (B,S,DIM)
    float* out_attn = out_x + (size_t)B_ * S_ * DIM_;      // (B,H,S,S)

    char* w = (char*)d_ws;
    bf16* qx_b  = (bf16*)(w + (size_t)0);          //  8 MiB
    bf16* kvx_b = (bf16*)(w + ((size_t)8  << 20)); //  8 MiB
    bf16* wq_b  = (bf16*)(w + ((size_t)16 << 20)); //  2 MiB
    bf16* wkv_b = (bf16*)(w + ((size_t)18 << 20)); //  4 MiB
    bf16* wpj_b = (bf16*)(w + ((size_t)22 << 20)); //  2 MiB
    bf16* qp    = (bf16*)(w + ((size_t)24 << 20)); //  8 MiB  (B,S,DIM)
    bf16* kvp   = (bf16*)(w + ((size_t)32 << 20)); // 16 MiB  (B,S,2*DIM)
    bf16* qr    = (bf16*)(w + ((size_t)48 << 20)); //  8 MiB  (B,H,S,HD)
    bf16* kr    = (bf16*)(w + ((size_t)56 << 20)); //  8 MiB
    bf16* vt    = (bf16*)(w + ((size_t)64 << 20)); //  8 MiB  (B,H,HD,S)
    bf16* ob    = (bf16*)(w + ((size_t)72 << 20)); //  8 MiB  (B,S,DIM)
    float* invU = (float*)(w + ((size_t)80 << 20)); // 256 KiB
    bf16* pbuf  = (bf16*)(w + ((size_t)96 << 20));  // 256 MiB (optional)

    const bool big_ws = ws_size >= (((size_t)96 << 20) + ((size_t)268435456) + (1 << 20));

    // f32 -> bf16 conversions
    cvt_kernel<<<4096, 256, 0, stream>>>(q_x,   qx_b,  1048576);
    cvt_kernel<<<4096, 256, 0, stream>>>(kv_x,  kvx_b, 1048576);
    cvt_kernel<<<1024, 256, 0, stream>>>(Wq,    wq_b,   262144);
    cvt_kernel<<<2048, 256, 0, stream>>>(Wkv,   wkv_b,  524288);
    cvt_kernel<<<1024, 256, 0, stream>>>(Wproj, wpj_b,  262144);

    // projections
    gemm_bt<0, 0><<<dim3(8, 32),  256, 0, stream>>>(qx_b,  wq_b,  qp,  nullptr, 4096, 1024, 1024);
    gemm_bt<0, 0><<<dim3(16, 32), 256, 0, stream>>>(kvx_b, wkv_b, kvp, nullptr, 4096, 2048, 1024);

    // RoPE + layout
    rope_kernel<<<2048, 256, 0, stream>>>(qp,  q_fr, qr, 1024, SCALE_);
    rope_kernel<<<2048, 256, 0, stream>>>(kvp, k_fr, kr, 2048, 1.0f);
    vtrans_kernel<<<1024, 256, 0, stream>>>(kvp, vt);

    // fused attention pass A + streaming pass B
    if (big_ws) {
        attn_fwd<0><<<1024, 256, 0, stream>>>(qr, kr, vt, maskp, prior, pbuf, invU, ob);
        attn_scale_t<<<32768, 256, 0, stream>>>(pbuf, invU, out_attn);
    } else {
        attn_fwd<1><<<1024, 256, 0, stream>>>(qr, kr, vt, maskp, prior, out_attn, invU, ob);
        attn_scale_ip<<<65536, 256, 0, stream>>>(out_attn, invU);
    }

    // output projection
    gemm_bt<1, 1><<<dim3(8, 32), 256, 0, stream>>>(ob, wpj_b, out_x, bproj, 4096, 1024, 1024);
}

// Round 4
// 517.430 us; speedup vs baseline: 1.3868x; 1.3599x over previous
//
#include <hip/hip_runtime.h>
#include <hip/hip_bf16.h>

typedef __bf16 bf16;
typedef __bf16 bf16x4 __attribute__((ext_vector_type(4)));
typedef __bf16 bf16x8 __attribute__((ext_vector_type(8)));
typedef float floatx4 __attribute__((ext_vector_type(4)));
typedef float float4v __attribute__((ext_vector_type(4)));

#define MFMA16(a, b, c) __builtin_amdgcn_mfma_f32_16x16x32_bf16(a, b, c, 0, 0, 0)

constexpr int B_ = 2, S_ = 2048, DIM_ = 1024, H_ = 16, HD_ = 64;
constexpr float SCALE_ = 0.125f;   // HD^-0.5
constexpr float EPS_ = 1e-8f;

// ---------------------------------------------------------------- helpers
__device__ __forceinline__ void gload_lds16(const bf16* g, bf16* l) {
    __builtin_amdgcn_global_load_lds(
        (const __attribute__((address_space(1))) void*)g,
        (__attribute__((address_space(3))) void*)l, 16, 0, 0);
}

// ---------------------------------------------------------------- f32 -> bf16
__global__ __launch_bounds__(256) void cvt_kernel(const float* __restrict__ in,
                                                  bf16* __restrict__ out, int n4) {
    int i = blockIdx.x * 256 + threadIdx.x;
    if (i >= n4) return;
    float4v v = ((const float4v*)in)[i];
    bf16x4 o;
    o[0] = (bf16)v[0]; o[1] = (bf16)v[1]; o[2] = (bf16)v[2]; o[3] = (bf16)v[3];
    ((bf16x4*)out)[i] = o;
}

// ---------------------------------------------------------------- GEMM C = A(MxK) * B(NxK)^T
template<int OUTF32, int BIASED>
__global__ __launch_bounds__(256) void gemm_bt(const bf16* __restrict__ A,
                                               const bf16* __restrict__ B,
                                               void* __restrict__ Cp,
                                               const float* __restrict__ bias,
                                               int M, int N, int K) {
    __shared__ bf16 As[128 * 64];
    __shared__ bf16 Bs[128 * 64];
    const int lane = threadIdx.x & 63, wid = threadIdx.x >> 6;
    const int colL = lane & 15, grp = lane >> 4;
    const int bm = blockIdx.y * 128, bn = blockIdx.x * 128;
    const int wr = wid >> 1, wc = wid & 1;

    floatx4 acc[4][4];
#pragma unroll
    for (int m = 0; m < 4; ++m)
#pragma unroll
        for (int n = 0; n < 4; ++n) acc[m][n] = (floatx4){0.f, 0.f, 0.f, 0.f};

    for (int k0 = 0; k0 < K; k0 += 64) {
#pragma unroll
        for (int i = 0; i < 4; ++i) {
            int c = wid * 256 + i * 64 + lane;
            int row = c >> 3, sub = c & 7;
            gload_lds16(A + (size_t)(bm + row) * K + k0 + sub * 8,
                        &As[(wid * 256 + i * 64) * 8]);
            gload_lds16(B + (size_t)(bn + row) * K + k0 + sub * 8,
                        &Bs[(wid * 256 + i * 64) * 8]);
        }
        __syncthreads();
#pragma unroll
        for (int ks = 0; ks < 2; ++ks) {
            bf16x8 af[4], bfr[4];
#pragma unroll
            for (int m = 0; m < 4; ++m)
                af[m] = *(const bf16x8*)(&As[(wr * 64 + m * 16 + colL) * 64 + ks * 32 + grp * 8]);
#pragma unroll
            for (int n = 0; n < 4; ++n)
                bfr[n] = *(const bf16x8*)(&Bs[(wc * 64 + n * 16 + colL) * 64 + ks * 32 + grp * 8]);
#pragma unroll
            for (int m = 0; m < 4; ++m)
#pragma unroll
                for (int n = 0; n < 4; ++n)
                    acc[m][n] = MFMA16(af[m], bfr[n], acc[m][n]);
        }
        __syncthreads();
    }

#pragma unroll
    for (int m = 0; m < 4; ++m)
#pragma unroll
        for (int n = 0; n < 4; ++n)
#pragma unroll
            for (int r = 0; r < 4; ++r) {
                int row = bm + wr * 64 + m * 16 + grp * 4 + r;
                int col = bn + wc * 64 + n * 16 + colL;
                float v = acc[m][n][r];
                if (BIASED) v += bias[col];
                if (OUTF32) ((float*)Cp)[(size_t)row * N + col] = v;
                else        ((bf16*)Cp)[(size_t)row * N + col] = (bf16)v;
            }
}

// ---------------------------------------------------------------- RoPE (+scale), (B,S,DIM-slice) -> (B,H,S,HD)
__global__ __launch_bounds__(256) void rope_kernel(const bf16* __restrict__ in,
                                                   const float* __restrict__ fr,
                                                   bf16* __restrict__ out,
                                                   int in_ld, float scale) {
    int tid = blockIdx.x * 256 + threadIdx.x;
    int j = tid & 7, h = (tid >> 3) & 15, s = (tid >> 7) & 2047, b = tid >> 18;
    bf16x8 x = *(const bf16x8*)(in + (size_t)(b * 2048 + s) * in_ld + h * 64 + j * 8);
    const float* f = fr + (size_t)(b * 2048 + s) * 64 + j * 4;
    bf16x8 o;
#pragma unroll
    for (int i = 0; i < 4; ++i) {
        float c = f[i], sn = f[32 + i];
        float x0 = (float)x[2 * i], x1 = (float)x[2 * i + 1];
        o[2 * i]     = (bf16)((x0 * c - x1 * sn) * scale);
        o[2 * i + 1] = (bf16)((x0 * sn + x1 * c) * scale);
    }
    *(bf16x8*)(out + ((size_t)(b * 16 + h) * 2048 + s) * 64 + j * 8) = o;
}

// ---------------------------------------------------------------- V transpose: KVp(B,S,2048) v-part -> Vt(B,H,HD,S)
__global__ __launch_bounds__(256) void vtrans_kernel(const bf16* __restrict__ KVp,
                                                     bf16* __restrict__ Vt) {
    int bid = blockIdx.x;
    int sb = bid & 31, h = (bid >> 5) & 15, b = bid >> 9;
    __shared__ bf16 tile[64][66];
    int tid = threadIdx.x;
#pragma unroll
    for (int i = 0; i < 2; ++i) {
        int c = tid + i * 256;
        int row = c >> 3, sub = c & 7;
        bf16x8 x = *(const bf16x8*)(KVp + (size_t)(b * 2048 + sb * 64 + row) * 2048
                                    + 1024 + h * 64 + sub * 8);
#pragma unroll
        for (int k = 0; k < 8; ++k) tile[row][sub * 8 + k] = x[k];
    }
    __syncthreads();
#pragma unroll
    for (int i = 0; i < 2; ++i) {
        int c = tid + i * 256;
        int drow = c >> 3, sub = c & 7;
        bf16x8 o;
#pragma unroll
        for (int k = 0; k < 8; ++k) o[k] = tile[sub * 8 + k][drow];
        *(bf16x8*)(Vt + ((size_t)(b * 16 + h) * 64 + drow) * 2048 + sb * 64 + sub * 8) = o;
    }
}

// ---------------------------------------------------------------- fused attention, two-phase, shift-free
// Block = (b,h,64 q rows), 4 waves x 16 q rows, full k sweep. K/V staged in LDS
// (double-buffered, pre-swizzled source). Phase 1: U + O accumulation. Phase 2:
// recompute logits from LDS-hot K, write attn = e*p*invU f32 directly.
__global__ __launch_bounds__(256) void attn_fused(const bf16* __restrict__ Qr,
                                                  const bf16* __restrict__ Kr,
                                                  const bf16* __restrict__ Vt,
                                                  const float* __restrict__ mask,
                                                  const float* __restrict__ prior,
                                                  float* __restrict__ attn_out,
                                                  bf16* __restrict__ O) {
    __shared__ bf16 KB[2][4096];
    __shared__ bf16 VB[2][4096];
    __shared__ bf16 plds[4][1024];

    const int tid = threadIdx.x;
    const int lane = tid & 63, wv = tid >> 6;
    const int colL = lane & 15, grp = lane >> 4;
    const int bidx = blockIdx.x;              // b*512 + h*32 + qb
    const int qb = bidx & 31, h = (bidx >> 5) & 15, b = bidx >> 9;
    const int bh = b * H_ + h;
    const int q0 = qb * 64 + wv * 16;

    const bf16* Qbase = Qr + ((size_t)bh * S_ + q0) * HD_;
    const bf16* Kbase = Kr + (size_t)bh * S_ * HD_;
    const bf16* Vbase = Vt + (size_t)bh * HD_ * S_;
    const float* Mrow = mask + ((size_t)b * S_ + q0 + colL) * S_;
    const float* Prow = prior + ((size_t)b * S_ + q0 + colL) * S_;

    bf16x8 qf0 = *(const bf16x8*)(Qbase + (size_t)colL * HD_ + grp * 8);
    bf16x8 qf1 = *(const bf16x8*)(Qbase + (size_t)colL * HD_ + 32 + grp * 8);

    bf16* P = plds[wv];
    const int swz = (colL & 7) << 3;
    const int c7 = colL & 7;

    // staging: chunk c = i*256+tid, row=c>>3, sub=c&7; source chunk pre-swizzled
    // (sub^row&7) so LDS reads by (row, d-chunk^row&7) are bank-even.
    auto stageK = [&](int buf, int k0) {
#pragma unroll
        for (int i = 0; i < 2; ++i) {
            int c = i * 256 + tid;
            int row = c >> 3, sub = c & 7;
            gload_lds16(Kbase + (size_t)(k0 + row) * HD_ + ((sub ^ (row & 7)) << 3),
                        &KB[buf][(c & ~63) << 3]);
        }
    };
    auto stageV = [&](int buf, int k0) {
#pragma unroll
        for (int i = 0; i < 2; ++i) {
            int c = i * 256 + tid;
            int row = c >> 3, sub = c & 7;
            gload_lds16(Vbase + (size_t)row * S_ + k0 + ((sub ^ (row & 7)) << 3),
                        &VB[buf][(c & ~63) << 3]);
        }
    };

    float ua = 0.f;
    floatx4 oT[4];
#pragma unroll
    for (int dt = 0; dt < 4; ++dt) oT[dt] = (floatx4){0.f, 0.f, 0.f, 0.f};

    float4v mk[4], pr[4];

    // ---------------- phase 1 prologue
    stageK(0, 0);
    stageV(0, 0);
#pragma unroll
    for (int ct = 0; ct < 4; ++ct) {
        mk[ct] = *(const float4v*)(Mrow + ct * 16 + grp * 4);
        pr[ct] = *(const float4v*)(Prow + ct * 16 + grp * 4);
    }
    __syncthreads();

    // ---------------- phase 1: U + O accumulation
    for (int kt = 0; kt < 32; ++kt) {
        const int k0 = kt * 64;
        const int cur = kt & 1;
        if (kt < 31) { stageK(cur ^ 1, k0 + 64); stageV(cur ^ 1, k0 + 64); }

        floatx4 s[4];
#pragma unroll
        for (int ct = 0; ct < 4; ++ct) {
            const int r8 = (ct * 16 + colL) * 8;
            bf16x8 a0 = *(const bf16x8*)&KB[cur][(r8 + (grp ^ c7)) * 8];
            bf16x8 a1 = *(const bf16x8*)&KB[cur][(r8 + (grp ^ 4 ^ c7)) * 8];
            floatx4 acc = (floatx4){0.f, 0.f, 0.f, 0.f};
            acc = MFMA16(a0, qf0, acc);
            acc = MFMA16(a1, qf1, acc);
            s[ct] = acc;
        }
        float4v cmk[4], cpr[4];
#pragma unroll
        for (int ct = 0; ct < 4; ++ct) { cmk[ct] = mk[ct]; cpr[ct] = pr[ct]; }
        if (kt < 31) {
#pragma unroll
            for (int ct = 0; ct < 4; ++ct) {
                mk[ct] = *(const float4v*)(Mrow + k0 + 64 + ct * 16 + grp * 4);
                pr[ct] = *(const float4v*)(Prow + k0 + 64 + ct * 16 + grp * 4);
            }
        }
#pragma unroll
        for (int ct = 0; ct < 4; ++ct) {
            bf16x4 pw;
#pragma unroll
            for (int r = 0; r < 4; ++r) {
                float e = __expf(s[ct][r] + cmk[ct][r]);
                float tv = e * fmaxf(cpr[ct][r], EPS_);
                ua += tv;
                pw[r] = (bf16)tv;
            }
            *(bf16x4*)&P[(colL * 64 + ct * 16 + grp * 4) ^ swz] = pw;
        }
#pragma unroll
        for (int ks = 0; ks < 2; ++ks) {
            bf16x8 pb = *(const bf16x8*)&P[(colL * 64 + ks * 32 + grp * 8) ^ swz];
#pragma unroll
            for (int dt = 0; dt < 4; ++dt) {
                const int r8 = (dt * 16 + colL) * 8;
                bf16x8 vf = *(const bf16x8*)&VB[cur][(r8 + ((ks * 4 + grp) ^ c7)) * 8];
                oT[dt] = MFMA16(vf, pb, oT[dt]);
            }
        }
        __syncthreads();
    }

    // ---------------- U reduce + O write
    ua += __shfl_xor(ua, 16, 64);
    ua += __shfl_xor(ua, 32, 64);
    const float iu = 1.0f / ua;
#pragma unroll
    for (int dt = 0; dt < 4; ++dt) {
        bf16x4 ow;
#pragma unroll
        for (int r = 0; r < 4; ++r) ow[r] = (bf16)(oT[dt][r] * iu);
        *(bf16x4*)(O + ((size_t)b * S_ + q0 + colL) * DIM_ + h * HD_ + dt * 16 + grp * 4) = ow;
    }

    // ---------------- phase 2 prologue
    stageK(0, 0);
#pragma unroll
    for (int ct = 0; ct < 4; ++ct) {
        mk[ct] = *(const float4v*)(Mrow + ct * 16 + grp * 4);
        pr[ct] = *(const float4v*)(Prow + ct * 16 + grp * 4);
    }
    __syncthreads();

    // ---------------- phase 2: recompute, write attn = e*p*invU
    float* Arow = attn_out + ((size_t)bh * S_ + q0 + colL) * S_;
    for (int kt = 0; kt < 32; ++kt) {
        const int k0 = kt * 64;
        const int cur = kt & 1;
        if (kt < 31) stageK(cur ^ 1, k0 + 64);

        floatx4 s[4];
#pragma unroll
        for (int ct = 0; ct < 4; ++ct) {
            const int r8 = (ct * 16 + colL) * 8;
            bf16x8 a0 = *(const bf16x8*)&KB[cur][(r8 + (grp ^ c7)) * 8];
            bf16x8 a1 = *(const bf16x8*)&KB[cur][(r8 + (grp ^ 4 ^ c7)) * 8];
            floatx4 acc = (floatx4){0.f, 0.f, 0.f, 0.f};
            acc = MFMA16(a0, qf0, acc);
            acc = MFMA16(a1, qf1, acc);
            s[ct] = acc;
        }
        float4v cmk[4], cpr[4];
#pragma unroll
        for (int ct = 0; ct < 4; ++ct) { cmk[ct] = mk[ct]; cpr[ct] = pr[ct]; }
        if (kt < 31) {
#pragma unroll
            for (int ct = 0; ct < 4; ++ct) {
                mk[ct] = *(const float4v*)(Mrow + k0 + 64 + ct * 16 + grp * 4);
                pr[ct] = *(const float4v*)(Prow + k0 + 64 + ct * 16 + grp * 4);
            }
        }
#pragma unroll
        for (int ct = 0; ct < 4; ++ct) {
            float4v o;
#pragma unroll
            for (int r = 0; r < 4; ++r)
                o[r] = __expf(s[ct][r] + cmk[ct][r]) * fmaxf(cpr[ct][r], EPS_) * iu;
            *(float4v*)(Arow + k0 + ct * 16 + grp * 4) = o;
        }
        __syncthreads();
    }
}

// ---------------------------------------------------------------- launch
extern "C" void kernel_launch(void* const* d_in, const int* in_sizes, int n_in,
                              void* d_out, int out_size, void* d_ws, size_t ws_size,
                              hipStream_t stream) {
    const float* q_x   = (const float*)d_in[0];
    const float* kv_x  = (const float*)d_in[1];
    const float* q_fr  = (const float*)d_in[2];
    const float* k_fr  = (const float*)d_in[3];
    const float* maskp = (const float*)d_in[4];
    const float* prior = (const float*)d_in[5];
    const float* Wq    = (const float*)d_in[6];
    const float* Wkv   = (const float*)d_in[7];
    const float* Wproj = (const float*)d_in[8];
    const float* bproj = (const float*)d_in[9];

    float* out_x    = (float*)d_out;                       // (B,S,DIM)
    float* out_attn = out_x + (size_t)B_ * S_ * DIM_;      // (B,H,S,S)

    char* w = (char*)d_ws;
    bf16* qx_b  = (bf16*)(w + (size_t)0);          //  8 MiB
    bf16* kvx_b = (bf16*)(w + ((size_t)8  << 20)); //  8 MiB
    bf16* wq_b  = (bf16*)(w + ((size_t)16 << 20)); //  2 MiB
    bf16* wkv_b = (bf16*)(w + ((size_t)18 << 20)); //  4 MiB
    bf16* wpj_b = (bf16*)(w + ((size_t)22 << 20)); //  2 MiB
    bf16* qp    = (bf16*)(w + ((size_t)24 << 20)); //  8 MiB  (B,S,DIM)
    bf16* kvp   = (bf16*)(w + ((size_t)32 << 20)); // 16 MiB  (B,S,2*DIM)
    bf16* qr    = (bf16*)(w + ((size_t)48 << 20)); //  8 MiB  (B,H,S,HD)
    bf16* kr    = (bf16*)(w + ((size_t)56 << 20)); //  8 MiB
    bf16* vt    = (bf16*)(w + ((size_t)64 << 20)); //  8 MiB  (B,H,HD,S)
    bf16* ob    = (bf16*)(w + ((size_t)72 << 20)); //  8 MiB  (B,S,DIM)

    // f32 -> bf16 conversions
    cvt_kernel<<<4096, 256, 0, stream>>>(q_x,   qx_b,  1048576);
    cvt_kernel<<<4096, 256, 0, stream>>>(kv_x,  kvx_b, 1048576);
    cvt_kernel<<<1024, 256, 0, stream>>>(Wq,    wq_b,   262144);
    cvt_kernel<<<2048, 256, 0, stream>>>(Wkv,   wkv_b,  524288);
    cvt_kernel<<<1024, 256, 0, stream>>>(Wproj, wpj_b,  262144);

    // projections
    gemm_bt<0, 0><<<dim3(8, 32),  256, 0, stream>>>(qx_b,  wq_b,  qp,  nullptr, 4096, 1024, 1024);
    gemm_bt<0, 0><<<dim3(16, 32), 256, 0, stream>>>(kvx_b, wkv_b, kvp, nullptr, 4096, 2048, 1024);

    // RoPE + layout
    rope_kernel<<<2048, 256, 0, stream>>>(qp,  q_fr, qr, 1024, SCALE_);
    rope_kernel<<<2048, 256, 0, stream>>>(kvp, k_fr, kr, 2048, 1.0f);
    vtrans_kernel<<<1024, 256, 0, stream>>>(kvp, vt);

    // fused attention: O + attn in one kernel
    attn_fused<<<1024, 256, 0, stream>>>(qr, kr, vt, maskp, prior, out_attn, ob);

    // output projection
    gemm_bt<1, 1><<<dim3(8, 32), 256, 0, stream>>>(ob, wpj_b, out_x, bproj, 4096, 1024, 1024);
}